// Round 7
// baseline (514.007 us; speedup 1.0000x reference)
//
#include <hip/hip_runtime.h>
#include <math.h>

// CapsuleRouting: u (8,144,16,16,12,12) f32, a (8,144,12,12) f32
// out: v (8,16,16,144) f32 ++ a_out (8,16,144) f32
//
// R7: fully dependency-free streaming decomposition.
//  P0: s0-partials, flat coalesced (1KB/instr) — gold-standard stream probe
//  D:  logit[b,B,c,pos] = a/16 + sum_p u.V   (no cross-lane, store 10.6 MB)
//  W:  e = exp(logit) in place; rden[b,B,pos] = 1/sum_c e   (tiny)
//  A:  s-partials += (e*rden) * u             (no cross-lane)
//  Q:  reduce 36 chunks + squash -> V / outputs
// No atomics, no barriers, no DPP/shfl anywhere in u-streaming kernels.

#define NB 8
#define BDIM 144
#define CDIM 16
#define PDIM 16
#define SDIM 144
#define PLANE (PDIM * SDIM)               // 2304
#define VELEMS (NB * CDIM * PLANE)        // 294912
#define AELEMS (NB * CDIM * SDIM)         // 18432
#define RELEMS (NB * BDIM * CDIM * SDIM)  // 2654208 (10.6 MB)
#define DENELEMS (NB * BDIM * SDIM)       // 165888
#define NCHUNK 36                         // per-wave partial chunks (4 B each)
#define BSTRIDE (CDIM * PLANE)            // 36864 floats between B's

__device__ __forceinline__ float4 ld4(const float* p) { return *(const float4*)p; }
__device__ __forceinline__ void st4(float* p, float4 v) { *(float4*)p = v; }

// ---- P0: iter-0 partial sums, flat plane layout, fully coalesced.
// grid (9, 16=c, 8=b), block 256 (4 waves). wave w: Bs {bx*16+4w+j}.
__global__ __launch_bounds__(256, 4) void p0_kernel(const float* __restrict__ u,
                                                    float* __restrict__ spart) {
  const int l = threadIdx.x & 63;
  const int w = threadIdx.x >> 6;
  const int c = blockIdx.y, b = blockIdx.z;
  const int B0 = blockIdx.x * 16 + w * 4;
  const float* pb = u + (size_t)((b * BDIM + B0) * CDIM + c) * PLANE + 4 * l;

  float4 sacc[9];
#pragma unroll
  for (int k = 0; k < 9; ++k) sacc[k] = make_float4(0.f, 0.f, 0.f, 0.f);
#pragma unroll 1
  for (int j = 0; j < 4; ++j) {
    const float* pj = pb + (size_t)j * BSTRIDE;
#pragma unroll
    for (int k = 0; k < 9; ++k) {
      const float4 x = ld4(pj + 256 * k);  // 64 lanes x 16B = 1KB contiguous
      sacc[k].x += x.x; sacc[k].y += x.y; sacc[k].z += x.z; sacc[k].w += x.w;
    }
  }
  float* sp = spart + (size_t)(blockIdx.x * 4 + w) * VELEMS +
              (size_t)(b * CDIM + c) * PLANE + 4 * l;
#pragma unroll
  for (int k = 0; k < 9; ++k) st4(sp + 256 * k, sacc[k]);
}

// ---- D: logit = a/16 + sum_p u.V -> R[b,B,c,pos]. grid (36,9,8), 4 waves.
__global__ __launch_bounds__(256, 4) void d_kernel(const float* __restrict__ u,
                                                   const float* __restrict__ a,
                                                   const float* __restrict__ V,
                                                   float* __restrict__ R) {
  const int l = threadIdx.x & 63;
  const int w = threadIdx.x >> 6;
  const int c = l & 15;
  const int posq = l >> 4;
  const int b = blockIdx.z;
  const int pos0 = blockIdx.y * 16 + posq * 4;
  const int B = blockIdx.x * 4 + w;

  const float* ub = u + ((size_t)((b * BDIM + B) * CDIM + c) * PDIM) * SDIM + pos0;
  const float* vb = V + ((size_t)(b * CDIM + c) * PDIM) * SDIM + pos0;

  float4 d = make_float4(0.f, 0.f, 0.f, 0.f);
#pragma unroll
  for (int p = 0; p < PDIM; ++p) {
    const float4 uv = ld4(ub + p * SDIM);
    const float4 vt = ld4(vb + p * SDIM);
    d.x += uv.x * vt.x; d.y += uv.y * vt.y;
    d.z += uv.z * vt.z; d.w += uv.w * vt.w;
  }
  const float4 a4 = ld4(a + (size_t)(b * BDIM + B) * SDIM + pos0);
  float4 lg;
  lg.x = fmaf(a4.x, 0.0625f, d.x); lg.y = fmaf(a4.y, 0.0625f, d.y);
  lg.z = fmaf(a4.z, 0.0625f, d.z); lg.w = fmaf(a4.w, 0.0625f, d.w);
  st4(R + (size_t)((b * BDIM + B) * CDIM + c) * SDIM + pos0, lg);
}

// ---- W: e = exp(logit) in place; rden = 1/sum_c e. thread per (b,B,pos).
__global__ __launch_bounds__(256) void w_kernel(float* __restrict__ R,
                                                float* __restrict__ rden) {
  const int gid = blockIdx.x * 256 + threadIdx.x;  // over DENELEMS
  const int pos = gid % SDIM;
  const int bB = gid / SDIM;
  float* rb = R + (size_t)bB * (CDIM * SDIM) + pos;
  float e[CDIM];
  float sum = 0.f;
#pragma unroll
  for (int c = 0; c < CDIM; ++c) {
    e[c] = __expf(rb[c * SDIM]);  // no-max softmax: logits O(10), fp32-safe
    sum += e[c];
  }
#pragma unroll
  for (int c = 0; c < CDIM; ++c) rb[c * SDIM] = e[c];
  rden[gid] = 1.0f / sum;
}

// ---- A: s-partials += (e*rden) * u. grid (9,9,8), 4 waves, 4 B per wave.
__global__ __launch_bounds__(256, 4) void a_kernel(const float* __restrict__ u,
                                                   const float* __restrict__ R,
                                                   const float* __restrict__ rden,
                                                   float* __restrict__ spart) {
  const int l = threadIdx.x & 63;
  const int w = threadIdx.x >> 6;
  const int c = l & 15;
  const int posq = l >> 4;
  const int b = blockIdx.z;
  const int pos0 = blockIdx.y * 16 + posq * 4;
  const int B0 = blockIdx.x * 16 + w * 4;

  const float* ub = u + ((size_t)((b * BDIM + B0) * CDIM + c) * PDIM) * SDIM + pos0;

  float4 sacc[PDIM];
#pragma unroll
  for (int p = 0; p < PDIM; ++p) sacc[p] = make_float4(0.f, 0.f, 0.f, 0.f);

#pragma unroll 1
  for (int j = 0; j < 4; ++j) {
    const int B = B0 + j;
    const float4 e4 = ld4(R + (size_t)((b * BDIM + B) * CDIM + c) * SDIM + pos0);
    const float4 r4 = ld4(rden + (size_t)(b * BDIM + B) * SDIM + pos0);
    float4 wt;
    wt.x = e4.x * r4.x; wt.y = e4.y * r4.y;
    wt.z = e4.z * r4.z; wt.w = e4.w * r4.w;
    const float* uj = ub + (size_t)j * BSTRIDE;
#pragma unroll
    for (int p = 0; p < PDIM; ++p) {
      const float4 uv = ld4(uj + p * SDIM);
      sacc[p].x += wt.x * uv.x; sacc[p].y += wt.y * uv.y;
      sacc[p].z += wt.z * uv.z; sacc[p].w += wt.w * uv.w;
    }
  }
  float* sp = spart + (size_t)(blockIdx.x * 4 + w) * VELEMS +
              ((size_t)(b * CDIM + c) * PDIM) * SDIM + pos0;
#pragma unroll
  for (int p = 0; p < PDIM; ++p) st4(sp + p * SDIM, sacc[p]);
}

// ---- Q: reduce 36 chunks, squash; mode 0: V=v*scale.. 1: V+=, 2: outputs.
__global__ __launch_bounds__(64) void q_kernel(const float* __restrict__ spart,
                                               float* __restrict__ V,
                                               float* __restrict__ out_v,
                                               float* __restrict__ out_a,
                                               float scale, int mode) {
  const int gid = blockIdx.x * 64 + threadIdx.x;  // over AELEMS
  const int pos = gid % SDIM;
  const int bc = gid / SDIM;
  const size_t base = (size_t)bc * PLANE + pos;

  float sv[PDIM];
#pragma unroll
  for (int p = 0; p < PDIM; ++p) sv[p] = 0.f;
#pragma unroll 1
  for (int k = 0; k < NCHUNK; ++k) {
    const float* sp = spart + (size_t)k * VELEMS + base;
#pragma unroll
    for (int p = 0; p < PDIM; ++p) sv[p] += sp[p * SDIM];
  }
  float sn = 0.f;
#pragma unroll
  for (int p = 0; p < PDIM; ++p) {
    sv[p] *= scale;
    sn += sv[p] * sv[p];
  }
  const float g = sn * __builtin_amdgcn_rcpf(1.f + sn);  // = ||squash(s)||
  const float sc = g * rsqrtf(sn);

  if (mode == 0) {
#pragma unroll
    for (int p = 0; p < PDIM; ++p) V[base + p * SDIM] = sv[p] * sc;
  } else if (mode == 1) {
#pragma unroll
    for (int p = 0; p < PDIM; ++p) V[base + p * SDIM] += sv[p] * sc;
  } else {
#pragma unroll
    for (int p = 0; p < PDIM; ++p) out_v[base + p * SDIM] = sv[p] * sc;
    out_a[gid] = g;
  }
}

extern "C" void kernel_launch(void* const* d_in, const int* in_sizes, int n_in,
                              void* d_out, int out_size, void* d_ws, size_t ws_size,
                              hipStream_t stream) {
  const float* u = (const float*)d_in[0];
  const float* a = (const float*)d_in[1];
  float* V = (float*)d_ws;                  // 1.18 MB
  float* spart = V + VELEMS;                // 36 x 1.18 MB = 42.5 MB
  float* R = spart + (size_t)NCHUNK * VELEMS;  // 10.6 MB
  float* rden = R + RELEMS;                 // 664 KB
  float* out_v = (float*)d_out;
  float* out_a = out_v + VELEMS;

  const dim3 gP0(9, CDIM, NB);   // 1152 blocks
  const dim3 gD(36, 9, NB);      // 2592 blocks
  const dim3 gA(9, 9, NB);       // 648 blocks
  const int gW = DENELEMS / 256; // 648
  const int gQ = AELEMS / 64;    // 288

  // iter 0 (uniform weights 1/16, folded into Q's scale)
  p0_kernel<<<gP0, 256, 0, stream>>>(u, spart);
  q_kernel<<<gQ, 64, 0, stream>>>(spart, V, out_v, out_a, 0.0625f, 0);
  // iter 1
  d_kernel<<<gD, 256, 0, stream>>>(u, a, V, R);
  w_kernel<<<gW, 256, 0, stream>>>(R, rden);
  a_kernel<<<gA, 256, 0, stream>>>(u, R, rden, spart);
  q_kernel<<<gQ, 64, 0, stream>>>(spart, V, out_v, out_a, 1.0f, 1);
  // iter 2
  d_kernel<<<gD, 256, 0, stream>>>(u, a, V, R);
  w_kernel<<<gW, 256, 0, stream>>>(R, rden);
  a_kernel<<<gA, 256, 0, stream>>>(u, R, rden, spart);
  q_kernel<<<gQ, 64, 0, stream>>>(spart, V, out_v, out_a, 1.0f, 2);
}